// Round 4
// baseline (85.521 us; speedup 1.0000x reference)
//
#include <hip/hip_runtime.h>

#define B_  4096
#define NH_ 64
#define NV_ 128

typedef float nfloat4 __attribute__((ext_vector_type(4)));

// Barrier-free design: each lane owns one float4 v-slice (NV=128 -> 32
// slices) of one batch element and loops over all 64 h. bTE accumulates
// in-register, wtTE streams out, tr reduces with a width-32 shuffle.
// No LDS, no __syncthreads -> waves are fully independent load streams.
__global__ __launch_bounds__(256)
void cpmte_kernel(const float* __restrict__ muvTE,       // [B,NV]
                  const float* __restrict__ varvhTE,     // [B,NH,NV]
                  const float* __restrict__ varh_diagTE, // [B,NH]
                  const float* __restrict__ varh_diag,   // [B,NH]
                  const float* __restrict__ muh,         // [B,NH]
                  const float* __restrict__ varvh,       // [B,NH,NV]
                  const float* __restrict__ muhTE,       // [B,NH]
                  const float* __restrict__ varvbarTE,   // [B]
                  const int*   __restrict__ nv_p,        // [1]
                  float* __restrict__ out_bTE,   // [B,NV]
                  float* __restrict__ out_wtTE,  // [B,NH,NV]
                  float* __restrict__ out_sig2,  // [B]
                  float* __restrict__ out_muhTE, // [B,NH]
                  float* __restrict__ out_vdTE)  // [B,NH]
{
    const int tid  = threadIdx.x;
    const int lane = tid & 63;
    const int wv   = tid >> 6;                          // wave 0..3
    const int b    = blockIdx.x * 8 + wv * 2 + (lane >> 5);
    const int v4   = lane & 31;                          // float4 slice of v

    // Passthrough outputs: this block covers 8 b's -> 512 [b,h] pairs.
    {
        const size_t base = (size_t)blockIdx.x * 8 * NH_;
        out_muhTE[base + tid]       = muhTE[base + tid];
        out_muhTE[base + tid + 256] = muhTE[base + tid + 256];
        out_vdTE [base + tid]       = varh_diagTE[base + tid];
        out_vdTE [base + tid + 256] = varh_diagTE[base + tid + 256];
    }

    const nfloat4* TEp = (const nfloat4*)(varvhTE + (size_t)b * NH_ * NV_);
    const nfloat4* VHp = (const nfloat4*)(varvh   + (size_t)b * NH_ * NV_);
    nfloat4*       WTp = (nfloat4*)(out_wtTE + (size_t)b * NH_ * NV_);

    const float* vdp   = varh_diag   + (size_t)b * NH_;
    const float* vdTEp = varh_diagTE + (size_t)b * NH_;
    const float* mp    = muh         + (size_t)b * NH_;
    const float* mTEp  = muhTE       + (size_t)b * NH_;

    nfloat4 accb = ((const nfloat4*)(muvTE + (size_t)b * NV_))[v4];
    float tr = 0.f;

    #pragma unroll 8
    for (int h = 0; h < NH_; ++h) {
        const nfloat4 t4 = TEp[h * (NV_ / 4) + v4];
        const nfloat4 vh = VHp[h * (NV_ / 4) + v4];

        // per-h coefficients: uniform across the 32-lane half-wave,
        // broadcast loads served by L1 (arrays are ~1 MB, L2-resident).
        const float vinv = 1.0f / vdp[h];
        const float vdTE = vdTEp[h];
        const float i1   = vinv * mp[h];                     // vinv*muh
        const float d23  = vinv * (vdTE * i1 - mTEp[h]);     // inner2-inner3
        const float wA   = -vinv * vinv * vdTE;

        accb.x += d23 * vh.x - i1 * t4.x;
        accb.y += d23 * vh.y - i1 * t4.y;
        accb.z += d23 * vh.z - i1 * t4.z;
        accb.w += d23 * vh.w - i1 * t4.w;

        nfloat4 wt;
        wt.x = wA * vh.x + vinv * t4.x;
        wt.y = wA * vh.y + vinv * t4.y;
        wt.z = wA * vh.z + vinv * t4.z;
        wt.w = wA * vh.w + vinv * t4.w;
        __builtin_nontemporal_store(wt, &WTp[h * (NV_ / 4) + v4]);

        // tr partial: VH*(2*vinv*TE + wA*VH)
        tr += vh.x * (2.f * vinv * t4.x + wA * vh.x);
        tr += vh.y * (2.f * vinv * t4.y + wA * vh.y);
        tr += vh.z * (2.f * vinv * t4.z + wA * vh.z);
        tr += vh.w * (2.f * vinv * t4.w + wA * vh.w);
    }

    ((nfloat4*)(out_bTE + (size_t)b * NV_))[v4] = accb;

    // tr: reduce over the 32 lanes that share this b
    #pragma unroll
    for (int off = 16; off >= 1; off >>= 1)
        tr += __shfl_down(tr, off, 32);
    if (v4 == 0)
        out_sig2[b] = (varvbarTE[b] - tr) / (float)nv_p[0];
}

extern "C" void kernel_launch(void* const* d_in, const int* in_sizes, int n_in,
                              void* d_out, int out_size, void* d_ws, size_t ws_size,
                              hipStream_t stream) {
    const float* muvTE       = (const float*)d_in[0];
    const float* varvhTE     = (const float*)d_in[1];
    const float* varh_diagTE = (const float*)d_in[2];
    const float* varh_diag   = (const float*)d_in[3];
    const float* muh         = (const float*)d_in[4];
    const float* varvh       = (const float*)d_in[5];
    const float* muhTE       = (const float*)d_in[6];
    const float* varvbarTE   = (const float*)d_in[7];
    const int*   nv_p        = (const int*)d_in[8];

    float* out = (float*)d_out;
    float* out_bTE   = out;
    float* out_wtTE  = out_bTE  + (size_t)B_ * NV_;
    float* out_sig2  = out_wtTE + (size_t)B_ * NH_ * NV_;
    float* out_muhTE = out_sig2 + (size_t)B_;
    float* out_vdTE  = out_muhTE + (size_t)B_ * NH_;

    dim3 grid(B_ / 8), block(256);
    cpmte_kernel<<<grid, block, 0, stream>>>(muvTE, varvhTE, varh_diagTE, varh_diag,
                                             muh, varvh, muhTE, varvbarTE, nv_p,
                                             out_bTE, out_wtTE, out_sig2,
                                             out_muhTE, out_vdTE);
}

// Round 5
// 73.662 us; speedup vs baseline: 1.1610x; 1.1610x over previous
//
#include <hip/hip_runtime.h>

#define B_  4096
#define NH_ 64
#define NV_ 128

typedef float nfloat4 __attribute__((ext_vector_type(4)));
typedef float nfloat2 __attribute__((ext_vector_type(2)));

// One wave per batch element b. Each lane owns one float2 slice of the
// 128-wide v dimension and loops over all 64 h:
//   - bTE accumulates entirely in-register (no cross-lane reduce needed)
//   - wtTE streams out with non-temporal float2 stores
//   - tr reduces with one wave-wide shuffle tree at the end
// Coefficients (4 per h) are computed lane-parallel (lane l -> h=l) and
// parked in a per-wave LDS slab, read back in-loop as uniform-address
// ds_read_b128 broadcasts. Same-wave producer/consumer => NO barriers.
__global__ __launch_bounds__(256, 4)
void cpmte_kernel(const float* __restrict__ muvTE,       // [B,NV]
                  const float* __restrict__ varvhTE,     // [B,NH,NV]
                  const float* __restrict__ varh_diagTE, // [B,NH]
                  const float* __restrict__ varh_diag,   // [B,NH]
                  const float* __restrict__ muh,         // [B,NH]
                  const float* __restrict__ varvh,       // [B,NH,NV]
                  const float* __restrict__ muhTE,       // [B,NH]
                  const float* __restrict__ varvbarTE,   // [B]
                  const int*   __restrict__ nv_p,        // [1]
                  float* __restrict__ out_bTE,   // [B,NV]
                  float* __restrict__ out_wtTE,  // [B,NH,NV]
                  float* __restrict__ out_sig2,  // [B]
                  float* __restrict__ out_muhTE, // [B,NH]
                  float* __restrict__ out_vdTE)  // [B,NH]
{
    const int tid  = threadIdx.x;
    const int lane = tid & 63;
    const int wv   = tid >> 6;                 // wave 0..3
    const int b    = blockIdx.x * 4 + wv;      // one b per wave

    __shared__ float s_coef[4][NH_][4];        // [wave][h][i1,d23,wA,vinv]

    // Passthrough outputs: block covers 4 b's = 256 [b,h] pairs, 1/thread.
    {
        const size_t pbase = (size_t)blockIdx.x * 4 * NH_;
        out_muhTE[pbase + tid] = muhTE[pbase + tid];
        out_vdTE [pbase + tid] = varh_diagTE[pbase + tid];
    }

    // Lane-parallel coefficient setup: lane l computes coeffs for h = l.
    {
        const size_t o = (size_t)b * NH_ + lane;
        const float vinv = 1.0f / varh_diag[o];
        const float vdTE = varh_diagTE[o];
        const float i1   = vinv * muh[o];                 // vinv*muh
        const float d23  = vinv * (vdTE * i1 - muhTE[o]); // inner2-inner3
        const nfloat4 c  = {i1, d23, -vinv * vinv * vdTE, vinv};
        *(nfloat4*)s_coef[wv][lane] = c;
        // same-wave LDS write->read: lgkmcnt handles ordering, no barrier
    }

    const nfloat2* TEp = (const nfloat2*)(varvhTE + (size_t)b * NH_ * NV_);
    const nfloat2* VHp = (const nfloat2*)(varvh   + (size_t)b * NH_ * NV_);
    nfloat2*       WTp = (nfloat2*)(out_wtTE + (size_t)b * NH_ * NV_);

    nfloat2 accb = ((const nfloat2*)(muvTE + (size_t)b * NV_))[lane];
    float tr = 0.f;

    #pragma unroll 8
    for (int h = 0; h < NH_; ++h) {
        const nfloat2 t2 = TEp[h * (NV_ / 2) + lane];
        const nfloat2 v2 = VHp[h * (NV_ / 2) + lane];
        const nfloat4 c  = *(const nfloat4*)s_coef[wv][h]; // broadcast read
        const float i1 = c.x, d23 = c.y, wA = c.z, vi = c.w;

        accb.x += d23 * v2.x - i1 * t2.x;
        accb.y += d23 * v2.y - i1 * t2.y;

        nfloat2 wt;
        wt.x = wA * v2.x + vi * t2.x;
        wt.y = wA * v2.y + vi * t2.y;
        __builtin_nontemporal_store(wt, &WTp[h * (NV_ / 2) + lane]);

        // tr partial: VH*(2*vi*TE + wA*VH)
        tr += v2.x * (2.f * vi * t2.x + wA * v2.x);
        tr += v2.y * (2.f * vi * t2.y + wA * v2.y);
    }

    ((nfloat2*)(out_bTE + (size_t)b * NV_))[lane] = accb;

    #pragma unroll
    for (int off = 32; off >= 1; off >>= 1)
        tr += __shfl_down(tr, off, 64);
    if (lane == 0)
        out_sig2[b] = (varvbarTE[b] - tr) / (float)nv_p[0];
}

extern "C" void kernel_launch(void* const* d_in, const int* in_sizes, int n_in,
                              void* d_out, int out_size, void* d_ws, size_t ws_size,
                              hipStream_t stream) {
    const float* muvTE       = (const float*)d_in[0];
    const float* varvhTE     = (const float*)d_in[1];
    const float* varh_diagTE = (const float*)d_in[2];
    const float* varh_diag   = (const float*)d_in[3];
    const float* muh         = (const float*)d_in[4];
    const float* varvh       = (const float*)d_in[5];
    const float* muhTE       = (const float*)d_in[6];
    const float* varvbarTE   = (const float*)d_in[7];
    const int*   nv_p        = (const int*)d_in[8];

    float* out = (float*)d_out;
    float* out_bTE   = out;
    float* out_wtTE  = out_bTE  + (size_t)B_ * NV_;
    float* out_sig2  = out_wtTE + (size_t)B_ * NH_ * NV_;
    float* out_muhTE = out_sig2 + (size_t)B_;
    float* out_vdTE  = out_muhTE + (size_t)B_ * NH_;

    dim3 grid(B_ / 4), block(256);
    cpmte_kernel<<<grid, block, 0, stream>>>(muvTE, varvhTE, varh_diagTE, varh_diag,
                                             muh, varvh, muhTE, varvbarTE, nv_p,
                                             out_bTE, out_wtTE, out_sig2,
                                             out_muhTE, out_vdTE);
}

// Round 6
// 66.225 us; speedup vs baseline: 1.2914x; 1.1123x over previous
//
#include <hip/hip_runtime.h>

#define B_  4096
#define NH_ 64
#define NV_ 128

typedef float nfloat4 __attribute__((ext_vector_type(4)));

// One wave per batch element. 64 lanes x float4 = 2 h-rows per iteration,
// 32 iterations over h. The wave's loads are CONTIGUOUS 1KB blocks
// (TE[64k+lane]) with pure immediate-offset addressing. Coefficients live
// in a per-wave LDS slab (lane-parallel setup, same-wave consume -> no
// barrier anywhere). bTE folds with one shfl_down(32); tr with a wave tree.
__global__ __launch_bounds__(256, 4)
void cpmte_kernel(const float* __restrict__ muvTE,       // [B,NV]
                  const float* __restrict__ varvhTE,     // [B,NH,NV]
                  const float* __restrict__ varh_diagTE, // [B,NH]
                  const float* __restrict__ varh_diag,   // [B,NH]
                  const float* __restrict__ muh,         // [B,NH]
                  const float* __restrict__ varvh,       // [B,NH,NV]
                  const float* __restrict__ muhTE,       // [B,NH]
                  const float* __restrict__ varvbarTE,   // [B]
                  const int*   __restrict__ nv_p,        // [1]
                  float* __restrict__ out_bTE,   // [B,NV]
                  float* __restrict__ out_wtTE,  // [B,NH,NV]
                  float* __restrict__ out_sig2,  // [B]
                  float* __restrict__ out_muhTE, // [B,NH]
                  float* __restrict__ out_vdTE)  // [B,NH]
{
    const int tid  = threadIdx.x;
    const int lane = tid & 63;
    const int wv   = tid >> 6;                 // wave 0..3
    const int b    = blockIdx.x * 4 + wv;      // one b per wave
    const int r    = lane >> 5;                // which h-row of the pair
    const int v4   = lane & 31;                // float4 slice of v

    __shared__ float s_coef[4][NH_][4];        // [wave][h][i1,d23,wA,vinv]

    // Passthrough outputs: block covers 4 b's = 256 [b,h] pairs, 1/thread.
    {
        const size_t pbase = (size_t)blockIdx.x * 4 * NH_;
        out_muhTE[pbase + tid] = muhTE[pbase + tid];
        out_vdTE [pbase + tid] = varh_diagTE[pbase + tid];
    }

    // Lane-parallel coefficient setup: lane l -> h = l. Same-wave LDS
    // write->read is ordered by lgkmcnt; no barrier needed.
    {
        const size_t o = (size_t)b * NH_ + lane;
        const float vinv = 1.0f / varh_diag[o];
        const float vdTE = varh_diagTE[o];
        const float i1   = vinv * muh[o];                 // vinv*muh
        const float d23  = vinv * (vdTE * i1 - muhTE[o]); // inner2-inner3
        const nfloat4 c  = {i1, d23, -vinv * vinv * vdTE, vinv};
        *(nfloat4*)s_coef[wv][lane] = c;
    }

    const nfloat4* TEp = (const nfloat4*)(varvhTE + (size_t)b * NH_ * NV_) + lane;
    const nfloat4* VHp = (const nfloat4*)(varvh   + (size_t)b * NH_ * NV_) + lane;
    nfloat4*       WTp = (nfloat4*)(out_wtTE + (size_t)b * NH_ * NV_) + lane;

    // muv for the final bTE store (lanes 0..31 own the result)
    nfloat4 muv = {0.f, 0.f, 0.f, 0.f};
    if (lane < 32) muv = ((const nfloat4*)(muvTE + (size_t)b * NV_))[lane];

    nfloat4 accb = {0.f, 0.f, 0.f, 0.f};
    float tr = 0.f;

    #pragma unroll 8
    for (int k = 0; k < 32; ++k) {
        const nfloat4 t4 = TEp[k * 64];        // wave-contiguous 1KB block
        const nfloat4 vh = VHp[k * 64];
        const nfloat4 c  = *(const nfloat4*)s_coef[wv][2 * k + r];
        const float i1 = c.x, d23 = c.y, wA = c.z, vi = c.w;

        accb.x += d23 * vh.x - i1 * t4.x;
        accb.y += d23 * vh.y - i1 * t4.y;
        accb.z += d23 * vh.z - i1 * t4.z;
        accb.w += d23 * vh.w - i1 * t4.w;

        nfloat4 wt;
        wt.x = wA * vh.x + vi * t4.x;
        wt.y = wA * vh.y + vi * t4.y;
        wt.z = wA * vh.z + vi * t4.z;
        wt.w = wA * vh.w + vi * t4.w;
        __builtin_nontemporal_store(wt, &WTp[k * 64]);

        // tr partial: VH*(2*vi*TE + wA*VH)
        tr += vh.x * (2.f * vi * t4.x + wA * vh.x);
        tr += vh.y * (2.f * vi * t4.y + wA * vh.y);
        tr += vh.z * (2.f * vi * t4.z + wA * vh.z);
        tr += vh.w * (2.f * vi * t4.w + wA * vh.w);
    }

    // Fold the two h-halves of bTE: lane v4 += lane v4+32.
    accb.x += __shfl_down(accb.x, 32, 64);
    accb.y += __shfl_down(accb.y, 32, 64);
    accb.z += __shfl_down(accb.z, 32, 64);
    accb.w += __shfl_down(accb.w, 32, 64);
    if (lane < 32) {
        nfloat4 o = {muv.x + accb.x, muv.y + accb.y,
                     muv.z + accb.z, muv.w + accb.w};
        ((nfloat4*)(out_bTE + (size_t)b * NV_))[lane] = o;
    }

    #pragma unroll
    for (int off = 32; off >= 1; off >>= 1)
        tr += __shfl_down(tr, off, 64);
    if (lane == 0)
        out_sig2[b] = (varvbarTE[b] - tr) / (float)nv_p[0];
}

extern "C" void kernel_launch(void* const* d_in, const int* in_sizes, int n_in,
                              void* d_out, int out_size, void* d_ws, size_t ws_size,
                              hipStream_t stream) {
    const float* muvTE       = (const float*)d_in[0];
    const float* varvhTE     = (const float*)d_in[1];
    const float* varh_diagTE = (const float*)d_in[2];
    const float* varh_diag   = (const float*)d_in[3];
    const float* muh         = (const float*)d_in[4];
    const float* varvh       = (const float*)d_in[5];
    const float* muhTE       = (const float*)d_in[6];
    const float* varvbarTE   = (const float*)d_in[7];
    const int*   nv_p        = (const int*)d_in[8];

    float* out = (float*)d_out;
    float* out_bTE   = out;
    float* out_wtTE  = out_bTE  + (size_t)B_ * NV_;
    float* out_sig2  = out_wtTE + (size_t)B_ * NH_ * NV_;
    float* out_muhTE = out_sig2 + (size_t)B_;
    float* out_vdTE  = out_muhTE + (size_t)B_ * NH_;

    dim3 grid(B_ / 4), block(256);
    cpmte_kernel<<<grid, block, 0, stream>>>(muvTE, varvhTE, varh_diagTE, varh_diag,
                                             muh, varvh, muhTE, varvbarTE, nv_p,
                                             out_bTE, out_wtTE, out_sig2,
                                             out_muhTE, out_vdTE);
}